// Round 2
// baseline (346.650 us; speedup 1.0000x reference)
//
#include <hip/hip_runtime.h>
#include <stdint.h>

#define EPS_F 1e-7f

typedef float f32x4 __attribute__((ext_vector_type(4)));

union A8 { uint2 u2; long l; };

__device__ __forceinline__ unsigned cvt4(float a, float b, float c, float d) {
  int v = __builtin_amdgcn_cvt_pk_fp8_f32(a, b, 0, false);   // bytes 0,1
  return (unsigned)__builtin_amdgcn_cvt_pk_fp8_f32(c, d, v, true);  // bytes 2,3
}

// ---------------------------------------------------------------------------
// prep: prototypes fp32 (2048x512) -> fp8 e4m3 in MFMA B-fragment order for
// 16x16x32 fp8.  16-B chunk (g,kp2), lane l (q=l>>4, cl=l&15) holds
// col n = 16g + cl;  bytes[0:8) = k [64*kp2 + 8q, +8)         (even K32-step)
//                    bytes[8:16) = k [64*kp2 + 32 + 8q, +8)   (odd  K32-step)
// Also y2[c] = ||p_c||^2 (fp32 exact) and ry[c] = 1/(1-y2), and out=0.
// ---------------------------------------------------------------------------
__global__ __launch_bounds__(256) void prep_kernel(
    const float* __restrict__ protos, uint8_t* __restrict__ wsB,
    float* __restrict__ y2a, float* __restrict__ rya,
    float* __restrict__ out) {
  const int lane = threadIdx.x & 63;
  const int w    = threadIdx.x >> 6;
  const int kp2  = lane >> 2, q = lane & 3;   // writer coords (lanes 0..31)
  const int sl0  = 8 * kp2 + q;               // source lane of even half
  const int sl1  = sl0 + 4;                   // source lane of odd half
  const int c = blockIdx.x * 4 + w;
  const float4* p = (const float4*)(protos + (size_t)c * 512 + lane * 8);
  float4 f0 = p[0], f1 = p[1];
  float s = f0.x*f0.x + f0.y*f0.y + f0.z*f0.z + f0.w*f0.w
          + f1.x*f1.x + f1.y*f1.y + f1.z*f1.z + f1.w*f1.w;
#pragma unroll
  for (int off = 32; off > 0; off >>= 1) s += __shfl_xor(s, off, 64);
  if (lane == 0) { y2a[c] = s; rya[c] = 1.f / (1.f - s); }
  unsigned ux = cvt4(f0.x, f0.y, f0.z, f0.w);   // this lane's k [8l, 8l+4)
  unsigned uy = cvt4(f1.x, f1.y, f1.z, f1.w);   // k [8l+4, 8l+8)
  uint4 ch;
  ch.x = __shfl((int)ux, sl0, 64);
  ch.y = __shfl((int)uy, sl0, 64);
  ch.z = __shfl((int)ux, sl1, 64);
  ch.w = __shfl((int)uy, sl1, 64);
  if (lane < 32) {
    int g = c >> 4, cl = c & 15;
    ((uint4*)wsB)[((size_t)g * 8 + kp2) * 64 + q * 16 + cl] = ch;
  }
  if (blockIdx.x == 0 && threadIdx.x == 0) out[0] = 0.f;
}

// ---------------------------------------------------------------------------
// gemm_min: 512 blocks x 512 thr (8 waves), launch_bounds(512,4) ->
// 2 blocks/CU resident = 16 waves/CU = 4 waves/SIMD.  Round-0 geometry
// (64 rows/block, 16 MFMA per {4 ds_read_b128 + 2 global b128} iter, 512 MB
// total B demand) kept intact — round-1 proved that halving the row tile
// doubles B traffic past L2 (FETCH 39->104 MB) and halves MFMA/B-byte; this
// version doubles occupancy by splitting COLUMNS 8 ways instead (256-col
// strip per wave, 64 outer iters instead of 128), leaving per-wave
// arithmetic intensity and register profile identical to round 0.
//   - A: 64 rows x 512 K fp8 staged ONCE into 32 KB LDS by waves 0..3
//     (identical per-wave volume to round 0); x2 fused fp32-exact.
//     ONE barrier before the main loop.
//   - B: register pipeline, depth 4 iters (8 b128 in flight, ~320 cyc of
//     MFMA cover per wave, x4 waves/SIMD TLP) from the L2-resident 1 MB
//     pre-swizzled image; warm-up issued BEFORE the staging barrier.
//   - epilogue per 32-col strip: tmin = min(tmin, max(x2+y2-2dot,0)*ry);
//     1/(1-x2) folded once per row at the end (monotone, rx>0).
// ---------------------------------------------------------------------------
__global__ __launch_bounds__(512, 4) void gemm_min_kernel(
    const float* __restrict__ z, const uint8_t* __restrict__ wsB,
    const float* __restrict__ y2a, const float* __restrict__ rya,
    const float* __restrict__ marg, float* __restrict__ out) {
  __shared__ uint8_t As[32 * 1024];   // 32 chunks (kp2*4 + rf) x 64 lanes x 16B
  __shared__ float x2s[64];
  __shared__ float rxs[64];
  __shared__ float minbuf[64][8];

  const int tid  = threadIdx.x;
  const int lane = tid & 63;
  const int w    = tid >> 6;          // wave 0..7
  const int q    = lane >> 4;         // quad 0..3
  const int l15  = lane & 15;
  const size_t rowbase = (size_t)blockIdx.x * 64;

  const uint4* Bg = (const uint4*)wsB;

  // ---- B pipeline warm-up first: overlaps the staging barrier wait ----
  // wave w owns cols [w*256, w*256+256): g in [w*16, w*16+16).
  // iter i = s*8 + kp2 (s=0..7) consumes chunks c0 = w*128 + s*16 + kp2
  // and c1 = c0 + 8; slot = i & 3.
  uint4 B0w[4], B1w[4];
#pragma unroll
  for (int i = 0; i < 4; ++i) {
    B0w[i] = Bg[(size_t)(w * 128 + i) * 64 + lane];
    B1w[i] = Bg[(size_t)(w * 128 + 8 + i) * 64 + lane];
  }

  // ---- A staging + fused x2: waves 0..3 own rows w*16 + l15 ----
  // lane (q,l15) covers k slices [64j+8q,+8) and [64j+32+8q,+8) for j=0..7
  if (w < 4) {
    const float* rp0 = z + (rowbase + w * 16 + l15) * 512;
    float s = 0.f;
#pragma unroll
    for (int j = 0; j < 8; ++j) {
      const float* rp = rp0 + j * 64 + q * 8;
      float4 a0 = ((const float4*)rp)[0];
      float4 a1 = ((const float4*)rp)[1];
      float4 b0 = ((const float4*)(rp + 32))[0];
      float4 b1 = ((const float4*)(rp + 32))[1];
      s += a0.x*a0.x + a0.y*a0.y + a0.z*a0.z + a0.w*a0.w
         + a1.x*a1.x + a1.y*a1.y + a1.z*a1.z + a1.w*a1.w
         + b0.x*b0.x + b0.y*b0.y + b0.z*b0.z + b0.w*b0.w
         + b1.x*b1.x + b1.y*b1.y + b1.z*b1.z + b1.w*b1.w;
      uint4 ch;
      ch.x = cvt4(a0.x, a0.y, a0.z, a0.w);
      ch.y = cvt4(a1.x, a1.y, a1.z, a1.w);
      ch.z = cvt4(b0.x, b0.y, b0.z, b0.w);
      ch.w = cvt4(b1.x, b1.y, b1.z, b1.w);
      ((uint4*)As)[(j * 4 + w) * 64 + lane] = ch;   // chunk = kp2*4 + rf(=w)
    }
    s += __shfl_xor(s, 16, 64);
    s += __shfl_xor(s, 32, 64);      // sum over the 4 q-lanes of this row
    if (lane < 16) { x2s[w * 16 + lane] = s; rxs[w * 16 + lane] = 1.f / (1.f - s); }
  }
  __syncthreads();  // the ONLY barrier before the final reduction

  // x2 resident per lane: rows rf*16 + q*4 + r
  float x2r[4][4];
#pragma unroll
  for (int rf = 0; rf < 4; ++rf) {
    float4 x4 = *(const float4*)&x2s[rf * 16 + q * 4];
    x2r[rf][0] = x4.x; x2r[rf][1] = x4.y; x2r[rf][2] = x4.z; x2r[rf][3] = x4.w;
  }

  const uint4* Ap = (const uint4*)As;

  float tmin[4][4];
#pragma unroll
  for (int rf = 0; rf < 4; ++rf)
#pragma unroll
    for (int r = 0; r < 4; ++r) tmin[rf][r] = 3.4e38f;

  const float* y2p = y2a + w * 256 + l15;
  const float* ryp = rya + w * 256 + l15;

#pragma clang loop unroll(disable)
  for (int s = 0; s < 8; ++s) {
    f32x4 acc[4][2];
#pragma unroll
    for (int rf = 0; rf < 4; ++rf) {
      f32x4 z4 = {0.f, 0.f, 0.f, 0.f};
      acc[rf][0] = z4; acc[rf][1] = z4;
    }
    float y2v0 = y2p[s * 32],      ryv0 = ryp[s * 32];
    float y2v1 = y2p[s * 32 + 16], ryv1 = ryp[s * 32 + 16];

#pragma unroll
    for (int kp2 = 0; kp2 < 8; ++kp2) {
      uint4 bu0 = B0w[kp2 & 3];
      uint4 bu1 = B1w[kp2 & 3];
      {  // prefetch iter i+4 into the just-freed slot (pad absorbs tail)
        int ip = s * 8 + kp2 + 4;
        int sp = ip >> 3, kq = ip & 7;
        size_t c0 = (size_t)(w * 128 + sp * 16 + kq) * 64 + lane;
        B0w[kp2 & 3] = Bg[c0];
        B1w[kp2 & 3] = Bg[c0 + 8 * 64];
      }
      A8 b0lo, b0hi, b1lo, b1hi;
      b0lo.u2 = make_uint2(bu0.x, bu0.y); b0hi.u2 = make_uint2(bu0.z, bu0.w);
      b1lo.u2 = make_uint2(bu1.x, bu1.y); b1hi.u2 = make_uint2(bu1.z, bu1.w);
#pragma unroll
      for (int rf = 0; rf < 4; ++rf) {
        uint4 av = Ap[(kp2 * 4 + rf) * 64 + lane];
        A8 alo, ahi;
        alo.u2 = make_uint2(av.x, av.y);
        ahi.u2 = make_uint2(av.z, av.w);
        acc[rf][0] = __builtin_amdgcn_mfma_f32_16x16x32_fp8_fp8(
            alo.l, b0lo.l, acc[rf][0], 0, 0, 0);
        acc[rf][1] = __builtin_amdgcn_mfma_f32_16x16x32_fp8_fp8(
            alo.l, b1lo.l, acc[rf][1], 0, 0, 0);
        acc[rf][0] = __builtin_amdgcn_mfma_f32_16x16x32_fp8_fp8(
            ahi.l, b0hi.l, acc[rf][0], 0, 0, 0);
        acc[rf][1] = __builtin_amdgcn_mfma_f32_16x16x32_fp8_fp8(
            ahi.l, b1hi.l, acc[rf][1], 0, 0, 0);
      }
    }

    // epilogue: cols c0 = w*256 + s*32 + l15, c1 = c0 + 16
#pragma unroll
    for (int rf = 0; rf < 4; ++rf) {
#pragma unroll
      for (int r = 0; r < 4; ++r) {
        float xv = x2r[rf][r];
        float u0 = fmaxf(fmaf(-2.f, acc[rf][0][r], xv + y2v0), 0.f) * ryv0;
        float u1 = fmaxf(fmaf(-2.f, acc[rf][1][r], xv + y2v1), 0.f) * ryv1;
        tmin[rf][r] = fminf(tmin[rf][r], fminf(u0, u1));
      }
    }
  }

  // ---- min across the 16 lanes (l15) sharing each row ----
#pragma unroll
  for (int rf = 0; rf < 4; ++rf) {
#pragma unroll
    for (int r = 0; r < 4; ++r) {
      float v = tmin[rf][r];
      v = fminf(v, __shfl_xor(v, 1, 64));
      v = fminf(v, __shfl_xor(v, 2, 64));
      v = fminf(v, __shfl_xor(v, 4, 64));
      v = fminf(v, __shfl_xor(v, 8, 64));
      if (l15 == 0) minbuf[rf * 16 + q * 4 + r][w] = v;
    }
  }
  __syncthreads();

  if (w == 0) {  // lane = row 0..63
    float m = minbuf[lane][0];
#pragma unroll
    for (int i = 1; i < 8; ++i) m = fminf(m, minbuf[lane][i]);
    float t = m * rxs[lane];                 // fold 1/(1-x2) once per row
    float arg = fmaxf(fmaf(2.f, t, 1.f), 1.f + EPS_F);
    float contrib = fmaxf(marg[0] - acoshf(arg), 0.f);
#pragma unroll
    for (int off = 32; off > 0; off >>= 1) contrib += __shfl_xor(contrib, off, 64);
    if (lane == 0) atomicAdd(out, contrib * (1.0f / 32768.f));
  }
}

// ---------------------------------------------------------------------------
extern "C" void kernel_launch(void* const* d_in, const int* in_sizes, int n_in,
                              void* d_out, int out_size, void* d_ws, size_t ws_size,
                              hipStream_t stream) {
  const float* z      = (const float*)d_in[0];  // 32768 x 512 fp32
  const float* protos = (const float*)d_in[1];  // 2048 x 512 fp32
  const float* marg   = (const float*)d_in[2];  // scalar
  float* out = (float*)d_out;
  uint8_t* wsB = (uint8_t*)d_ws;                                 // 1 MB image
  // 192 KB pad absorbs the harmless B-pipeline tail over-reads (<= 64 KB).
  float* y2a = (float*)((char*)d_ws + (1 << 20) + 192 * 1024);   // 8 KB
  float* rya = y2a + 2048;                                       // 8 KB

  prep_kernel<<<512, 256, 0, stream>>>(protos, wsB, y2a, rya, out);
  gemm_min_kernel<<<512, 512, 0, stream>>>(z, wsB, y2a, rya, marg, out);
}

// Round 3
// 169.419 us; speedup vs baseline: 2.0461x; 2.0461x over previous
//
#include <hip/hip_runtime.h>
#include <stdint.h>

#define EPS_F 1e-7f

typedef float f32x4 __attribute__((ext_vector_type(4)));

union A8 { uint2 u2; long l; };

__device__ __forceinline__ unsigned cvt4(float a, float b, float c, float d) {
  int v = __builtin_amdgcn_cvt_pk_fp8_f32(a, b, 0, false);   // bytes 0,1
  return (unsigned)__builtin_amdgcn_cvt_pk_fp8_f32(c, d, v, true);  // bytes 2,3
}

// ---------------------------------------------------------------------------
// prep: prototypes fp32 (2048x512) -> fp8 e4m3 in MFMA B-fragment order for
// 16x16x32 fp8.  16-B chunk (g,kp2), lane l (q=l>>4, cl=l&15) holds
// col n = 16g + cl;  bytes[0:8) = k [64*kp2 + 8q, +8)         (even K32-step)
//                    bytes[8:16) = k [64*kp2 + 32 + 8q, +8)   (odd  K32-step)
// Also y2[c] = ||p_c||^2 (fp32 exact) and ry[c] = 1/(1-y2), and out=0.
// ---------------------------------------------------------------------------
__global__ __launch_bounds__(256) void prep_kernel(
    const float* __restrict__ protos, uint8_t* __restrict__ wsB,
    float* __restrict__ y2a, float* __restrict__ rya,
    float* __restrict__ out) {
  const int lane = threadIdx.x & 63;
  const int w    = threadIdx.x >> 6;
  const int kp2  = lane >> 2, q = lane & 3;   // writer coords (lanes 0..31)
  const int sl0  = 8 * kp2 + q;               // source lane of even half
  const int sl1  = sl0 + 4;                   // source lane of odd half
  const int c = blockIdx.x * 4 + w;
  const float4* p = (const float4*)(protos + (size_t)c * 512 + lane * 8);
  float4 f0 = p[0], f1 = p[1];
  float s = f0.x*f0.x + f0.y*f0.y + f0.z*f0.z + f0.w*f0.w
          + f1.x*f1.x + f1.y*f1.y + f1.z*f1.z + f1.w*f1.w;
#pragma unroll
  for (int off = 32; off > 0; off >>= 1) s += __shfl_xor(s, off, 64);
  if (lane == 0) { y2a[c] = s; rya[c] = 1.f / (1.f - s); }
  unsigned ux = cvt4(f0.x, f0.y, f0.z, f0.w);   // this lane's k [8l, 8l+4)
  unsigned uy = cvt4(f1.x, f1.y, f1.z, f1.w);   // k [8l+4, 8l+8)
  uint4 ch;
  ch.x = __shfl((int)ux, sl0, 64);
  ch.y = __shfl((int)uy, sl0, 64);
  ch.z = __shfl((int)ux, sl1, 64);
  ch.w = __shfl((int)uy, sl1, 64);
  if (lane < 32) {
    int g = c >> 4, cl = c & 15;
    ((uint4*)wsB)[((size_t)g * 8 + kp2) * 64 + q * 16 + cl] = ch;
  }
  if (blockIdx.x == 0 && threadIdx.x == 0) out[0] = 0.f;
}

// ---------------------------------------------------------------------------
// gemm_min: 512 blocks x 512 thr (8 waves).
// LAUNCH_BOUNDS NOTE (empirical, rounds 0-2): hipcc derives the VGPR cap
// from the 2nd arg as waves_per_eu = arg * threads/32 / 4 (warp-32-style):
//   (256,2)->cap 128 (R0, no spill); (256,4)->cap 64 (R1, spill);
//   (512,4)->cap 64 (R2, WRITE_SIZE 187 MB of scratch, MfmaUtil 10%).
// (512,1) -> waves_per_eu 4 -> VGPR cap 128 = exactly the R0 budget this
// main loop fits in.  At <=128 VGPR, 2 blocks/CU co-resident = 16 waves/CU
// = 4 waves/SIMD: R0 arithmetic intensity x2 occupancy.
//   - geometry: 64 rows/block (B demand stays 512 MB total, L2-resident;
//     R1 proved 32-row tiles push B past L2: FETCH 39->104 MB), 8-wave
//     column split (256-col strip per wave, 64 outer iters).
//   - A: 64 rows x 512 K fp8 staged ONCE into 32 KB LDS by waves 0..3;
//     x2 fused fp32-exact.  ONE barrier before the main loop.
//   - B: register pipeline, depth 4 iters (8 b128 in flight) from the
//     L2-resident 1 MB pre-swizzled image; warm-up issued BEFORE the
//     staging barrier.
//   - per iter (K=64): 4 ds_read_b128 (A), 2 global b128 (B), 16 MFMAs.
//   - epilogue per 32-col strip: tmin = min(tmin, max(x2+y2-2dot,0)*ry);
//     1/(1-x2) folded once per row at the end (monotone, rx>0).
// ---------------------------------------------------------------------------
__global__ __launch_bounds__(512, 1) void gemm_min_kernel(
    const float* __restrict__ z, const uint8_t* __restrict__ wsB,
    const float* __restrict__ y2a, const float* __restrict__ rya,
    const float* __restrict__ marg, float* __restrict__ out) {
  __shared__ uint8_t As[32 * 1024];   // 32 chunks (kp2*4 + rf) x 64 lanes x 16B
  __shared__ float x2s[64];
  __shared__ float rxs[64];
  __shared__ float minbuf[64][8];

  const int tid  = threadIdx.x;
  const int lane = tid & 63;
  const int w    = tid >> 6;          // wave 0..7
  const int q    = lane >> 4;         // quad 0..3
  const int l15  = lane & 15;
  const size_t rowbase = (size_t)blockIdx.x * 64;

  const uint4* Bg = (const uint4*)wsB;

  // ---- B pipeline warm-up first: overlaps the staging barrier wait ----
  // wave w owns cols [w*256, w*256+256): g in [w*16, w*16+16).
  // iter i = s*8 + kp2 (s=0..7) consumes chunks c0 = w*128 + s*16 + kp2
  // and c1 = c0 + 8; slot = i & 3.
  uint4 B0w[4], B1w[4];
#pragma unroll
  for (int i = 0; i < 4; ++i) {
    B0w[i] = Bg[(size_t)(w * 128 + i) * 64 + lane];
    B1w[i] = Bg[(size_t)(w * 128 + 8 + i) * 64 + lane];
  }

  // ---- A staging + fused x2: waves 0..3 own rows w*16 + l15 ----
  // lane (q,l15) covers k slices [64j+8q,+8) and [64j+32+8q,+8) for j=0..7
  if (w < 4) {
    const float* rp0 = z + (rowbase + w * 16 + l15) * 512;
    float s = 0.f;
#pragma unroll
    for (int j = 0; j < 8; ++j) {
      const float* rp = rp0 + j * 64 + q * 8;
      float4 a0 = ((const float4*)rp)[0];
      float4 a1 = ((const float4*)rp)[1];
      float4 b0 = ((const float4*)(rp + 32))[0];
      float4 b1 = ((const float4*)(rp + 32))[1];
      s += a0.x*a0.x + a0.y*a0.y + a0.z*a0.z + a0.w*a0.w
         + a1.x*a1.x + a1.y*a1.y + a1.z*a1.z + a1.w*a1.w
         + b0.x*b0.x + b0.y*b0.y + b0.z*b0.z + b0.w*b0.w
         + b1.x*b1.x + b1.y*b1.y + b1.z*b1.z + b1.w*b1.w;
      uint4 ch;
      ch.x = cvt4(a0.x, a0.y, a0.z, a0.w);
      ch.y = cvt4(a1.x, a1.y, a1.z, a1.w);
      ch.z = cvt4(b0.x, b0.y, b0.z, b0.w);
      ch.w = cvt4(b1.x, b1.y, b1.z, b1.w);
      ((uint4*)As)[(j * 4 + w) * 64 + lane] = ch;   // chunk = kp2*4 + rf(=w)
    }
    s += __shfl_xor(s, 16, 64);
    s += __shfl_xor(s, 32, 64);      // sum over the 4 q-lanes of this row
    if (lane < 16) { x2s[w * 16 + lane] = s; rxs[w * 16 + lane] = 1.f / (1.f - s); }
  }
  __syncthreads();  // the ONLY barrier before the final reduction

  // x2 resident per lane: rows rf*16 + q*4 + r
  float x2r[4][4];
#pragma unroll
  for (int rf = 0; rf < 4; ++rf) {
    float4 x4 = *(const float4*)&x2s[rf * 16 + q * 4];
    x2r[rf][0] = x4.x; x2r[rf][1] = x4.y; x2r[rf][2] = x4.z; x2r[rf][3] = x4.w;
  }

  const uint4* Ap = (const uint4*)As;

  float tmin[4][4];
#pragma unroll
  for (int rf = 0; rf < 4; ++rf)
#pragma unroll
    for (int r = 0; r < 4; ++r) tmin[rf][r] = 3.4e38f;

  const float* y2p = y2a + w * 256 + l15;
  const float* ryp = rya + w * 256 + l15;

#pragma clang loop unroll(disable)
  for (int s = 0; s < 8; ++s) {
    f32x4 acc[4][2];
#pragma unroll
    for (int rf = 0; rf < 4; ++rf) {
      f32x4 z4 = {0.f, 0.f, 0.f, 0.f};
      acc[rf][0] = z4; acc[rf][1] = z4;
    }
    float y2v0 = y2p[s * 32],      ryv0 = ryp[s * 32];
    float y2v1 = y2p[s * 32 + 16], ryv1 = ryp[s * 32 + 16];

#pragma unroll
    for (int kp2 = 0; kp2 < 8; ++kp2) {
      uint4 bu0 = B0w[kp2 & 3];
      uint4 bu1 = B1w[kp2 & 3];
      {  // prefetch iter i+4 into the just-freed slot (pad absorbs tail)
        int ip = s * 8 + kp2 + 4;
        int sp = ip >> 3, kq = ip & 7;
        size_t c0 = (size_t)(w * 128 + sp * 16 + kq) * 64 + lane;
        B0w[kp2 & 3] = Bg[c0];
        B1w[kp2 & 3] = Bg[c0 + 8 * 64];
      }
      A8 b0lo, b0hi, b1lo, b1hi;
      b0lo.u2 = make_uint2(bu0.x, bu0.y); b0hi.u2 = make_uint2(bu0.z, bu0.w);
      b1lo.u2 = make_uint2(bu1.x, bu1.y); b1hi.u2 = make_uint2(bu1.z, bu1.w);
#pragma unroll
      for (int rf = 0; rf < 4; ++rf) {
        uint4 av = Ap[(kp2 * 4 + rf) * 64 + lane];
        A8 alo, ahi;
        alo.u2 = make_uint2(av.x, av.y);
        ahi.u2 = make_uint2(av.z, av.w);
        acc[rf][0] = __builtin_amdgcn_mfma_f32_16x16x32_fp8_fp8(
            alo.l, b0lo.l, acc[rf][0], 0, 0, 0);
        acc[rf][1] = __builtin_amdgcn_mfma_f32_16x16x32_fp8_fp8(
            alo.l, b1lo.l, acc[rf][1], 0, 0, 0);
        acc[rf][0] = __builtin_amdgcn_mfma_f32_16x16x32_fp8_fp8(
            ahi.l, b0hi.l, acc[rf][0], 0, 0, 0);
        acc[rf][1] = __builtin_amdgcn_mfma_f32_16x16x32_fp8_fp8(
            ahi.l, b1hi.l, acc[rf][1], 0, 0, 0);
      }
    }

    // epilogue: cols c0 = w*256 + s*32 + l15, c1 = c0 + 16
#pragma unroll
    for (int rf = 0; rf < 4; ++rf) {
#pragma unroll
      for (int r = 0; r < 4; ++r) {
        float xv = x2r[rf][r];
        float u0 = fmaxf(fmaf(-2.f, acc[rf][0][r], xv + y2v0), 0.f) * ryv0;
        float u1 = fmaxf(fmaf(-2.f, acc[rf][1][r], xv + y2v1), 0.f) * ryv1;
        tmin[rf][r] = fminf(tmin[rf][r], fminf(u0, u1));
      }
    }
  }

  // ---- min across the 16 lanes (l15) sharing each row ----
#pragma unroll
  for (int rf = 0; rf < 4; ++rf) {
#pragma unroll
    for (int r = 0; r < 4; ++r) {
      float v = tmin[rf][r];
      v = fminf(v, __shfl_xor(v, 1, 64));
      v = fminf(v, __shfl_xor(v, 2, 64));
      v = fminf(v, __shfl_xor(v, 4, 64));
      v = fminf(v, __shfl_xor(v, 8, 64));
      if (l15 == 0) minbuf[rf * 16 + q * 4 + r][w] = v;
    }
  }
  __syncthreads();

  if (w == 0) {  // lane = row 0..63
    float m = minbuf[lane][0];
#pragma unroll
    for (int i = 1; i < 8; ++i) m = fminf(m, minbuf[lane][i]);
    float t = m * rxs[lane];                 // fold 1/(1-x2) once per row
    float arg = fmaxf(fmaf(2.f, t, 1.f), 1.f + EPS_F);
    float contrib = fmaxf(marg[0] - acoshf(arg), 0.f);
#pragma unroll
    for (int off = 32; off > 0; off >>= 1) contrib += __shfl_xor(contrib, off, 64);
    if (lane == 0) atomicAdd(out, contrib * (1.0f / 32768.f));
  }
}

// ---------------------------------------------------------------------------
extern "C" void kernel_launch(void* const* d_in, const int* in_sizes, int n_in,
                              void* d_out, int out_size, void* d_ws, size_t ws_size,
                              hipStream_t stream) {
  const float* z      = (const float*)d_in[0];  // 32768 x 512 fp32
  const float* protos = (const float*)d_in[1];  // 2048 x 512 fp32
  const float* marg   = (const float*)d_in[2];  // scalar
  float* out = (float*)d_out;
  uint8_t* wsB = (uint8_t*)d_ws;                                 // 1 MB image
  // 192 KB pad absorbs the harmless B-pipeline tail over-reads (<= 64 KB).
  float* y2a = (float*)((char*)d_ws + (1 << 20) + 192 * 1024);   // 8 KB
  float* rya = y2a + 2048;                                       // 8 KB

  prep_kernel<<<512, 256, 0, stream>>>(protos, wsB, y2a, rya, out);
  gemm_min_kernel<<<512, 512, 0, stream>>>(z, wsB, y2a, rya, marg, out);
}